// Round 1
// baseline (514.672 us; speedup 1.0000x reference)
//
#include <hip/hip_runtime.h>

#define DD 64
#define RR 12
#define KTOT 832   // 768 (A·Wrel) + 64 (h·(Wself+Wskip))
#define NKS 26     // 832 / 32 k-steps
#define ASTR 840   // LDS A row stride in halfs (420 words ≡ 4 mod 32: even banks)
#define TROWS 32   // nodes per block tile (2 MFMA row-groups share one B read)
#define EPB2 8192  // edges per block in bucket passes

typedef _Float16 half8v __attribute__((ext_vector_type(8)));
typedef __attribute__((ext_vector_type(4))) float f32x4;

// ---------------- h0 = relu(x * W_emb + b_emb), x is [N,1]; also fp16 copy ----
__global__ void k_h0(const float* __restrict__ x, const float* __restrict__ Wemb,
                     const float* __restrict__ bemb, float* __restrict__ h0,
                     _Float16* __restrict__ h16, int N) {
    int idx = blockIdx.x * blockDim.x + threadIdx.x;
    if (idx >= N * DD) return;
    int n = idx >> 6, d = idx & 63;
    float v = x[n] * Wemb[d] + bemb[d];
    v = v > 0.f ? v : 0.f;
    h0[idx] = v;
    h16[idx] = (_Float16)v;
}

// EW[n*12+r] = (ev, ev*gate)
__global__ void k_sgw(const float* __restrict__ h, const float* __restrict__ q,
                      const float* __restrict__ g, const float* __restrict__ gb,
                      float2* __restrict__ EW, int N) {
    int t = blockIdx.x * blockDim.x + threadIdx.x;
    if (t >= N * RR) return;
    int n = t / RR, r = t - n * RR;
    const float4* hp = (const float4*)(h + (size_t)n * DD);
    const float4* qp = (const float4*)(q + (size_t)r * DD);
    const float4* gp = (const float4*)(g + (size_t)r * DD);
    float sq = 0.f, sg = 0.f;
#pragma unroll
    for (int k = 0; k < 16; k++) {
        float4 hv = hp[k], qv = qp[k], gv = gp[k];
        sq += hv.x * qv.x + hv.y * qv.y + hv.z * qv.z + hv.w * qv.w;
        sg += hv.x * gv.x + hv.y * gv.y + hv.z * gv.z + hv.w * gv.w;
    }
    float sc = sq > 0.f ? sq : 0.01f * sq;       // leaky_relu
    float ev = expf(sc);                          // softmax max-shift invariant
    float gate = 1.f / (1.f + expf(-(sg + gb[0])));
    EW[t] = make_float2(ev, ev * gate);
}

// ============ coalesced two-level counting sort by dst ============
// bucket = dst >> 7 (128 nodes per bucket). payload u32 = dlow<<20 | et<<16 | src

__global__ void k_bh(const int* __restrict__ dst, int* __restrict__ bcnt,
                     int E, int nbuck) {
    __shared__ int lh[512];
    int tid = threadIdx.x;
    for (int i = tid; i < 512; i += 512) lh[i] = 0;
    __syncthreads();
    int base = blockIdx.x * EPB2;
    int lim = base + EPB2 < E ? base + EPB2 : E;
    for (int i = base + tid; i < lim; i += 512)
        atomicAdd(&lh[dst[i] >> 7], 1);
    __syncthreads();
    for (int i = tid; i < nbuck; i += 512)
        if (lh[i]) atomicAdd(&bcnt[i], lh[i]);
}

__global__ void k_bscan(const int* __restrict__ bcnt, int* __restrict__ bbase,
                        int* __restrict__ bcur, int nbuck, int E) {
    __shared__ int wsum[8];
    int tid = threadIdx.x, lane = tid & 63, wv = tid >> 6;
    int v = (tid < nbuck) ? bcnt[tid] : 0;
    int incl = v;
#pragma unroll
    for (int d = 1; d < 64; d <<= 1) {
        int t2 = __shfl_up(incl, d);
        if (lane >= d) incl += t2;
    }
    if (lane == 63) wsum[wv] = incl;
    __syncthreads();
    int pre = 0;
#pragma unroll
    for (int w = 0; w < 8; w++) if (w < wv) pre += wsum[w];
    int excl = pre + incl - v;
    if (tid < nbuck) { bbase[tid] = excl; bcur[tid] = excl; }
    if (tid == nbuck - 1) bbase[nbuck] = excl + v;   // == E
}

__global__ void k_bscat(const int* __restrict__ src, const int* __restrict__ dst,
                        const int* __restrict__ et, int* __restrict__ bcur,
                        unsigned* __restrict__ epk2, int E, int nbuck) {
    __shared__ int lh[512];
    __shared__ int lcur[512];
    int tid = threadIdx.x;
    for (int i = tid; i < 512; i += 512) lh[i] = 0;
    __syncthreads();
    int base = blockIdx.x * EPB2;
    int lim = base + EPB2 < E ? base + EPB2 : E;
    for (int i = base + tid; i < lim; i += 512)
        atomicAdd(&lh[dst[i] >> 7], 1);
    __syncthreads();
    for (int i = tid; i < nbuck; i += 512)
        lcur[i] = lh[i] ? atomicAdd(&bcur[i], lh[i]) : 0;
    __syncthreads();
    for (int i = base + tid; i < lim; i += 512) {
        int d = dst[i];
        int pos = atomicAdd(&lcur[d >> 7], 1);
        epk2[pos] = ((unsigned)(d & 127) << 20) | ((unsigned)et[i] << 16) | (unsigned)src[i];
    }
}

__global__ void k_b2(const unsigned* __restrict__ epk2, const int* __restrict__ bbase,
                     unsigned* __restrict__ epk, int* __restrict__ offd,
                     int N, int E) {
    int b = blockIdx.x, tid = threadIdx.x;
    int p0 = bbase[b], p1 = bbase[b + 1], cb = p1 - p0;
    __shared__ int hist[128], cur[128];
    __shared__ unsigned stg[4096];
    if (tid < 128) hist[tid] = 0;
    __syncthreads();
    for (int i = tid; i < cb; i += 256)
        atomicAdd(&hist[(epk2[p0 + i] >> 20) & 127], 1);
    __syncthreads();
    if (tid == 0) {
        int a = 0;
        for (int j = 0; j < 128; j++) { int c = hist[j]; hist[j] = a; a += c; }
    }
    __syncthreads();
    if (tid < 128) {
        cur[tid] = hist[tid];
        int node = b * 128 + tid;
        if (node < N) offd[node] = p0 + hist[tid];
    }
    if (b == 0 && tid == 0) offd[N] = E;
    __syncthreads();
    if (cb <= 4096) {
        for (int i = tid; i < cb; i += 256) {
            unsigned pk = epk2[p0 + i];
            int pos = atomicAdd(&cur[(pk >> 20) & 127], 1);
            stg[pos] = pk & 0xFFFFFu;
        }
        __syncthreads();
        for (int i = tid; i < cb; i += 256) epk[p0 + i] = stg[i];
    } else {   // statistically never; correctness fallback
        for (int i = tid; i < cb; i += 256) {
            unsigned pk = epk2[p0 + i];
            int pos = atomicAdd(&cur[(pk >> 20) & 127], 1);
            epk[p0 + pos] = pk & 0xFFFFFu;
        }
    }
}

// -------- weight prep: blocks 0..25 = B fragments (fp16 hi/lo planes);
//          blocks 26..28 = q/g projection vectors --------
__global__ void k_wprep(const float* __restrict__ Wrel, const float* __restrict__ Wself,
                        const float* __restrict__ Wskip, const float* __restrict__ av,
                        const float* __restrict__ gw,
                        _Float16* __restrict__ Bh, _Float16* __restrict__ Bl,
                        float* __restrict__ q, float* __restrict__ g) {
    int bx = blockIdx.x;
    if (bx < NKS) {
        int t = bx * 256 + threadIdx.x;
        int ks = t >> 8, ct = (t >> 6) & 3, lane = t & 63;
        int col = ct * 16 + (lane & 15);
        int kb = ks * 32 + ((lane >> 4) << 3);
        _Float16* ph = Bh + (size_t)t * 8;
        _Float16* pl = Bl + (size_t)t * 8;
#pragma unroll
        for (int i = 0; i < 8; i++) {
            int k = kb + i;
            float v;
            if (k < 768) v = Wrel[(size_t)k * DD + col];
            else {
                v = Wself[(size_t)(k - 768) * DD + col];
                if (Wskip) v += Wskip[(size_t)(k - 768) * DD + col];
            }
            _Float16 h = (_Float16)v;
            ph[i] = h;
            pl[i] = (_Float16)(v - (float)h);
        }
    } else {
        int t = (bx - NKS) * 256 + threadIdx.x;
        if (t >= RR * DD) return;
        const float* wp = Wrel + (size_t)t * DD;
        float aq = 0.f, ag = 0.f;
#pragma unroll
        for (int e = 0; e < DD; e++) { float w = wp[e]; aq += w * av[e]; ag += w * gw[e]; }
        q[t] = aq; g[t] = ag;
    }
}

// ---------------- fused layer kernel: aggregate -> LDS A-tile -> MFMA ------
// Phase 1: per-edge uniform epk load, uniform float2 EW gather (ev, ev*gate)
// riding the same latency chain as the h16 row gather; Z accumulated
// in-register (the claiming wave sees all of a node's edges).
// Phase 2: 32-row tile, each of 4 waves applies one B read (bh+bl) to TWO
// A row-group fragments -> B L2 traffic per node halved vs 16-row tile.
#define AGG_EDGE(ee, wy, hh)                                       \
    switch (ee) {                                                  \
        case 0:  acc[0]  = fmaf(wy, hh, acc[0]);  break;           \
        case 1:  acc[1]  = fmaf(wy, hh, acc[1]);  break;           \
        case 2:  acc[2]  = fmaf(wy, hh, acc[2]);  break;           \
        case 3:  acc[3]  = fmaf(wy, hh, acc[3]);  break;           \
        case 4:  acc[4]  = fmaf(wy, hh, acc[4]);  break;           \
        case 5:  acc[5]  = fmaf(wy, hh, acc[5]);  break;           \
        case 6:  acc[6]  = fmaf(wy, hh, acc[6]);  break;           \
        case 7:  acc[7]  = fmaf(wy, hh, acc[7]);  break;           \
        case 8:  acc[8]  = fmaf(wy, hh, acc[8]);  break;           \
        case 9:  acc[9]  = fmaf(wy, hh, acc[9]);  break;           \
        case 10: acc[10] = fmaf(wy, hh, acc[10]); break;           \
        default: acc[11] = fmaf(wy, hh, acc[11]); break;           \
    }

__global__ void __launch_bounds__(512, 8)
k_fused(const unsigned* __restrict__ epk, const int* __restrict__ offd,
        const _Float16* __restrict__ hin16, const float2* __restrict__ EW,
        const _Float16* __restrict__ Bh, const _Float16* __restrict__ Bl,
        const float* __restrict__ bias, float* __restrict__ out,
        _Float16* __restrict__ hout16, int N, int act) {
    __shared__ __align__(16) _Float16 At[TROWS * ASTR];
    __shared__ int claim;
    int tid = threadIdx.x, lane = tid & 63, w = tid >> 6;
    int nb0 = blockIdx.x * TROWS;
    if (tid == 0) claim = 0;
    __syncthreads();

    // ---- phase 1: waves claim nodes until the tile is done ----
    for (;;) {
        int t0 = 0;
        if (lane == 0) t0 = atomicAdd(&claim, 1);
        int nl = __builtin_amdgcn_readfirstlane(t0);
        if (nl >= TROWS) break;
        int node = nb0 + nl;
        _Float16* Ar = At + nl * ASTR;
        if (node >= N) {
            for (int k = lane; k < KTOT; k += 64) Ar[k] = (_Float16)0.f;
            continue;
        }
        int p0 = __builtin_amdgcn_readfirstlane(offd[node]);
        int p1 = __builtin_amdgcn_readfirstlane(offd[node + 1]);
        float acc[RR];
#pragma unroll
        for (int r = 0; r < RR; r++) acc[r] = 0.f;
        float zacc = 0.f;
        int p = p0;
        for (; p + 8 <= p1; p += 8) {
            unsigned pk0 = epk[p + 0], pk1 = epk[p + 1], pk2 = epk[p + 2], pk3 = epk[p + 3];
            unsigned pk4 = epk[p + 4], pk5 = epk[p + 5], pk6 = epk[p + 6], pk7 = epk[p + 7];
            float2 ew0 = EW[(pk0 & 0xFFFFu) * RR + ((pk0 >> 16) & 15u)];
            float2 ew1 = EW[(pk1 & 0xFFFFu) * RR + ((pk1 >> 16) & 15u)];
            float2 ew2 = EW[(pk2 & 0xFFFFu) * RR + ((pk2 >> 16) & 15u)];
            float2 ew3 = EW[(pk3 & 0xFFFFu) * RR + ((pk3 >> 16) & 15u)];
            float2 ew4 = EW[(pk4 & 0xFFFFu) * RR + ((pk4 >> 16) & 15u)];
            float2 ew5 = EW[(pk5 & 0xFFFFu) * RR + ((pk5 >> 16) & 15u)];
            float2 ew6 = EW[(pk6 & 0xFFFFu) * RR + ((pk6 >> 16) & 15u)];
            float2 ew7 = EW[(pk7 & 0xFFFFu) * RR + ((pk7 >> 16) & 15u)];
            float hv[8];
            hv[0] = (float)hin16[(size_t)(pk0 & 0xFFFFu) * DD + lane];
            hv[1] = (float)hin16[(size_t)(pk1 & 0xFFFFu) * DD + lane];
            hv[2] = (float)hin16[(size_t)(pk2 & 0xFFFFu) * DD + lane];
            hv[3] = (float)hin16[(size_t)(pk3 & 0xFFFFu) * DD + lane];
            hv[4] = (float)hin16[(size_t)(pk4 & 0xFFFFu) * DD + lane];
            hv[5] = (float)hin16[(size_t)(pk5 & 0xFFFFu) * DD + lane];
            hv[6] = (float)hin16[(size_t)(pk6 & 0xFFFFu) * DD + lane];
            hv[7] = (float)hin16[(size_t)(pk7 & 0xFFFFu) * DD + lane];
            int e0 = __builtin_amdgcn_readfirstlane((int)((pk0 >> 16) & 15u));
            int e1 = __builtin_amdgcn_readfirstlane((int)((pk1 >> 16) & 15u));
            int e2 = __builtin_amdgcn_readfirstlane((int)((pk2 >> 16) & 15u));
            int e3 = __builtin_amdgcn_readfirstlane((int)((pk3 >> 16) & 15u));
            int e4 = __builtin_amdgcn_readfirstlane((int)((pk4 >> 16) & 15u));
            int e5 = __builtin_amdgcn_readfirstlane((int)((pk5 >> 16) & 15u));
            int e6 = __builtin_amdgcn_readfirstlane((int)((pk6 >> 16) & 15u));
            int e7 = __builtin_amdgcn_readfirstlane((int)((pk7 >> 16) & 15u));
            zacc += ((ew0.x + ew1.x) + (ew2.x + ew3.x)) + ((ew4.x + ew5.x) + (ew6.x + ew7.x));
            AGG_EDGE(e0, ew0.y, hv[0]);
            AGG_EDGE(e1, ew1.y, hv[1]);
            AGG_EDGE(e2, ew2.y, hv[2]);
            AGG_EDGE(e3, ew3.y, hv[3]);
            AGG_EDGE(e4, ew4.y, hv[4]);
            AGG_EDGE(e5, ew5.y, hv[5]);
            AGG_EDGE(e6, ew6.y, hv[6]);
            AGG_EDGE(e7, ew7.y, hv[7]);
        }
        for (; p < p1; ++p) {
            unsigned pk = epk[p];
            float2 ewv = EW[(pk & 0xFFFFu) * RR + ((pk >> 16) & 15u)];
            float hv = (float)hin16[(size_t)(pk & 0xFFFFu) * DD + lane];
            int e = __builtin_amdgcn_readfirstlane((int)((pk >> 16) & 15u));
            zacc += ewv.x;
            AGG_EDGE(e, ewv.y, hv);
        }
        float inv = 1.f / (zacc + 1e-16f);
#pragma unroll
        for (int r = 0; r < RR; r++) Ar[r * DD + lane] = (_Float16)(acc[r] * inv);
        Ar[768 + lane] = hin16[(size_t)node * DD + lane];   // self/skip cols
    }
    __syncthreads();

    // ---- phase 2: waves 0-3 compute col-tiles (16 cols each), 2 row-groups ----
    if (w < 4) {
        const half8v* Bh8 = (const half8v*)Bh;
        const half8v* Bl8 = (const half8v*)Bl;
        const _Float16* abase = At + (lane & 15) * ASTR + ((lane >> 4) << 3);
        f32x4 accA = {0.f, 0.f, 0.f, 0.f};
        f32x4 accB = {0.f, 0.f, 0.f, 0.f};
#pragma unroll 2
        for (int ks = 0; ks < NKS; ++ks) {
            half8v ah0 = *(const half8v*)(abase + ks * 32);
            half8v ah1 = *(const half8v*)(abase + 16 * ASTR + ks * 32);
            size_t bb = (size_t)(ks * 4 + w) * 64 + lane;
            half8v bh = Bh8[bb];
            half8v bl = Bl8[bb];
            accA = __builtin_amdgcn_mfma_f32_16x16x32_f16(ah0, bh, accA, 0, 0, 0);
            accA = __builtin_amdgcn_mfma_f32_16x16x32_f16(ah0, bl, accA, 0, 0, 0);
            accB = __builtin_amdgcn_mfma_f32_16x16x32_f16(ah1, bh, accB, 0, 0, 0);
            accB = __builtin_amdgcn_mfma_f32_16x16x32_f16(ah1, bl, accB, 0, 0, 0);
        }

        // epilogue: D layout col=lane&15, row=(lane>>4)*4+j
        int colb = lane & 15, kg = lane >> 4;
        int c = w * 16 + colb;
        float bv = bias[c];
#pragma unroll
        for (int j = 0; j < 4; j++) {
            int row = nb0 + kg * 4 + j;
            if (row < N) {
                float v = accA[j] + bv;
                if (act) v = v > 0.f ? v : 0.f;
                out[(size_t)row * DD + c] = v;
                if (hout16) hout16[(size_t)row * DD + c] = (_Float16)v;
            }
            int row2 = nb0 + 16 + kg * 4 + j;
            if (row2 < N) {
                float v = accB[j] + bv;
                if (act) v = v > 0.f ? v : 0.f;
                out[(size_t)row2 * DD + c] = v;
                if (hout16) hout16[(size_t)row2 * DD + c] = (_Float16)v;
            }
        }
    }
}

extern "C" void kernel_launch(void* const* d_in, const int* in_sizes, int n_in,
                              void* d_out, int out_size, void* d_ws, size_t ws_size,
                              hipStream_t stream) {
    const float* x    = (const float*)d_in[0];
    const int*   src  = (const int*)d_in[1];
    const int*   dst  = (const int*)d_in[2];
    const int*   etyp = (const int*)d_in[3];
    const float* Wemb = (const float*)d_in[4];
    const float* bemb = (const float*)d_in[5];
    const int N = in_sizes[0];
    const int E = in_sizes[1];
    const int nbuck = (N + 127) >> 7;
    const int nblk2 = (E + EPB2 - 1) / EPB2;

    const float* Wrel[3];  const float* Wself[3]; const float* bb[3];
    const float* gwv[3];   const float* gbv[3];   const float* av[3];
    for (int l = 0; l < 3; l++) {
        int o = 6 + 6 * l;
        Wrel[l]  = (const float*)d_in[o + 0];
        Wself[l] = (const float*)d_in[o + 1];
        bb[l]    = (const float*)d_in[o + 2];
        gwv[l]   = (const float*)d_in[o + 3];
        gbv[l]   = (const float*)d_in[o + 4];
        av[l]    = (const float*)d_in[o + 5];
    }
    const float* Wskip2 = (const float*)d_in[24];
    const float* Wskip3 = (const float*)d_in[25];

    // ---- workspace ----
    float* p = (float*)d_ws;
    float* h0 = p; p += (size_t)N * DD;
    float* h1 = p; p += (size_t)N * DD;
    float* h2 = p; p += (size_t)N * DD;
    _Float16* h16A = (_Float16*)p; p += (size_t)N * DD / 2;   // fp16 copy (ping)
    _Float16* h16B = (_Float16*)p; p += (size_t)N * DD / 2;   // fp16 copy (pong)
    float2* EW = (float2*)p; p += (size_t)N * RR * 2;
    float* q  = p; p += RR * DD;
    float* g  = p; p += RR * DD;
    _Float16* Bh = (_Float16*)p; p += NKS * 4 * 64 * 8 / 2;
    _Float16* Bl = (_Float16*)p; p += NKS * 4 * 64 * 8 / 2;
    unsigned* epk2 = (unsigned*)p; p += E;
    unsigned* epk  = (unsigned*)p; p += E;
    int* bcnt  = (int*)p; p += 512;
    int* bbase = (int*)p; p += 516;
    int* bcur  = (int*)p; p += 512;
    int* offd  = (int*)p; p += N + 4;

    const int B = 256;
    k_h0<<<(N * DD + B - 1) / B, B, 0, stream>>>(x, Wemb, bemb, h0, h16A, N);

    // coalesced two-level dst-sort (once; reused by all layers)
    hipMemsetAsync(bcnt, 0, 512 * 4, stream);
    k_bh<<<nblk2, 512, 0, stream>>>(dst, bcnt, E, nbuck);
    k_bscan<<<1, 512, 0, stream>>>(bcnt, bbase, bcur, nbuck, E);
    k_bscat<<<nblk2, 512, 0, stream>>>(src, dst, etyp, bcur, epk2, E, nbuck);
    k_b2<<<nbuck, 256, 0, stream>>>(epk2, bbase, epk, offd, N, E);

    const int fblocks = (N + TROWS - 1) / TROWS;
    // hin (f32) for scores; hin16 for gather; hout16 written for next layer
    auto layer = [&](const float* hin, const _Float16* hin16, float* hout,
                     _Float16* hout16, int l, const float* Wskip, int act) {
        k_wprep<<<NKS + 3, B, 0, stream>>>(Wrel[l], Wself[l], Wskip, av[l], gwv[l],
                                           Bh, Bl, q, g);
        k_sgw<<<(N * RR + B - 1) / B, B, 0, stream>>>(hin, q, g, gbv[l], EW, N);
        k_fused<<<fblocks, 512, 0, stream>>>(epk, offd, hin16, EW, Bh, Bl,
                                             bb[l], hout, hout16, N, act);
    };

    layer(h0, h16A, h1, h16B, 0, nullptr, 1);
    layer(h1, h16B, h2, h16A, 1, Wskip2, 1);
    layer(h2, h16A, (float*)d_out, nullptr, 2, Wskip3, 0);
}

// Round 2
// 365.767 us; speedup vs baseline: 1.4071x; 1.4071x over previous
//
#include <hip/hip_runtime.h>

#define DD 64
#define RR 12
#define KTOT 832   // 768 (A·Wrel) + 64 (h·(Wself+Wskip))
#define NKS 26     // 832 / 32 k-steps
#define ASTR 840   // LDS A row stride in halfs (420 words ≡ 4 mod 32: even banks)
#define EPB2 8192  // edges per block in bucket passes

typedef _Float16 half8v __attribute__((ext_vector_type(8)));
typedef __attribute__((ext_vector_type(4))) float f32x4;

// ---------------- h0 = relu(x * W_emb + b_emb), x is [N,1]; also fp16 copy ----
__global__ void k_h0(const float* __restrict__ x, const float* __restrict__ Wemb,
                     const float* __restrict__ bemb, float* __restrict__ h0,
                     _Float16* __restrict__ h16, int N) {
    int idx = blockIdx.x * blockDim.x + threadIdx.x;
    if (idx >= N * DD) return;
    int n = idx >> 6, d = idx & 63;
    float v = x[n] * Wemb[d] + bemb[d];
    v = v > 0.f ? v : 0.f;
    h0[idx] = v;
    h16[idx] = (_Float16)v;
}

// EW[n*12+r] = (ev, ev*gate)
__global__ void k_sgw(const float* __restrict__ h, const float* __restrict__ q,
                      const float* __restrict__ g, const float* __restrict__ gb,
                      float2* __restrict__ EW, int N) {
    int t = blockIdx.x * blockDim.x + threadIdx.x;
    if (t >= N * RR) return;
    int n = t / RR, r = t - n * RR;
    const float4* hp = (const float4*)(h + (size_t)n * DD);
    const float4* qp = (const float4*)(q + (size_t)r * DD);
    const float4* gp = (const float4*)(g + (size_t)r * DD);
    float sq = 0.f, sg = 0.f;
#pragma unroll
    for (int k = 0; k < 16; k++) {
        float4 hv = hp[k], qv = qp[k], gv = gp[k];
        sq += hv.x * qv.x + hv.y * qv.y + hv.z * qv.z + hv.w * qv.w;
        sg += hv.x * gv.x + hv.y * gv.y + hv.z * gv.z + hv.w * gv.w;
    }
    float sc = sq > 0.f ? sq : 0.01f * sq;       // leaky_relu
    float ev = expf(sc);                          // softmax max-shift invariant
    float gate = 1.f / (1.f + expf(-(sg + gb[0])));
    EW[t] = make_float2(ev, ev * gate);
}

// ---- per-edge weight stream: wE = ev*gate, evv = ev (sorted-edge order) ----
__global__ void k_ew(const unsigned* __restrict__ epk, const float2* __restrict__ EW,
                     float* __restrict__ wE, float* __restrict__ evv, int E) {
    int t = blockIdx.x * blockDim.x + threadIdx.x;
    if (t >= E) return;
    unsigned pk = epk[t];
    int s = (int)(pk & 0xFFFFu);
    int e = (int)((pk >> 16) & 15u);
    float2 ew = EW[(size_t)s * RR + e];
    wE[t] = ew.y;
    evv[t] = ew.x;
}

// ---- per-node softmax denominator: Z[n] = sum evv over the node's range ----
__global__ void k_zn(const float* __restrict__ evv, const int* __restrict__ offd,
                     float* __restrict__ Z, int N) {
    int n = blockIdx.x * blockDim.x + threadIdx.x;
    if (n >= N) return;
    int a = offd[n], b = offd[n + 1];
    float z = 0.f;
    for (int p = a; p < b; ++p) z += evv[p];
    Z[n] = z;
}

// ============ coalesced two-level counting sort by dst ============
// bucket = dst >> 7 (128 nodes per bucket). payload u32 = dlow<<20 | et<<16 | src

__global__ void k_bh(const int* __restrict__ dst, int* __restrict__ bcnt,
                     int E, int nbuck) {
    __shared__ int lh[512];
    int tid = threadIdx.x;
    for (int i = tid; i < 512; i += 512) lh[i] = 0;
    __syncthreads();
    int base = blockIdx.x * EPB2;
    int lim = base + EPB2 < E ? base + EPB2 : E;
    for (int i = base + tid; i < lim; i += 512)
        atomicAdd(&lh[dst[i] >> 7], 1);
    __syncthreads();
    for (int i = tid; i < nbuck; i += 512)
        if (lh[i]) atomicAdd(&bcnt[i], lh[i]);
}

__global__ void k_bscan(const int* __restrict__ bcnt, int* __restrict__ bbase,
                        int* __restrict__ bcur, int nbuck, int E) {
    __shared__ int wsum[8];
    int tid = threadIdx.x, lane = tid & 63, wv = tid >> 6;
    int v = (tid < nbuck) ? bcnt[tid] : 0;
    int incl = v;
#pragma unroll
    for (int d = 1; d < 64; d <<= 1) {
        int t2 = __shfl_up(incl, d);
        if (lane >= d) incl += t2;
    }
    if (lane == 63) wsum[wv] = incl;
    __syncthreads();
    int pre = 0;
#pragma unroll
    for (int w = 0; w < 8; w++) if (w < wv) pre += wsum[w];
    int excl = pre + incl - v;
    if (tid < nbuck) { bbase[tid] = excl; bcur[tid] = excl; }
    if (tid == nbuck - 1) bbase[nbuck] = excl + v;   // == E
}

__global__ void k_bscat(const int* __restrict__ src, const int* __restrict__ dst,
                        const int* __restrict__ et, int* __restrict__ bcur,
                        unsigned* __restrict__ epk2, int E, int nbuck) {
    __shared__ int lh[512];
    __shared__ int lcur[512];
    int tid = threadIdx.x;
    for (int i = tid; i < 512; i += 512) lh[i] = 0;
    __syncthreads();
    int base = blockIdx.x * EPB2;
    int lim = base + EPB2 < E ? base + EPB2 : E;
    for (int i = base + tid; i < lim; i += 512)
        atomicAdd(&lh[dst[i] >> 7], 1);
    __syncthreads();
    for (int i = tid; i < nbuck; i += 512)
        lcur[i] = lh[i] ? atomicAdd(&bcur[i], lh[i]) : 0;
    __syncthreads();
    for (int i = base + tid; i < lim; i += 512) {
        int d = dst[i];
        int pos = atomicAdd(&lcur[d >> 7], 1);
        epk2[pos] = ((unsigned)(d & 127) << 20) | ((unsigned)et[i] << 16) | (unsigned)src[i];
    }
}

__global__ void k_b2(const unsigned* __restrict__ epk2, const int* __restrict__ bbase,
                     unsigned* __restrict__ epk, int* __restrict__ offd,
                     int N, int E) {
    int b = blockIdx.x, tid = threadIdx.x;
    int p0 = bbase[b], p1 = bbase[b + 1], cb = p1 - p0;
    __shared__ int hist[128], cur[128];
    __shared__ unsigned stg[4096];
    if (tid < 128) hist[tid] = 0;
    __syncthreads();
    for (int i = tid; i < cb; i += 256)
        atomicAdd(&hist[(epk2[p0 + i] >> 20) & 127], 1);
    __syncthreads();
    if (tid == 0) {
        int a = 0;
        for (int j = 0; j < 128; j++) { int c = hist[j]; hist[j] = a; a += c; }
    }
    __syncthreads();
    if (tid < 128) {
        cur[tid] = hist[tid];
        int node = b * 128 + tid;
        if (node < N) offd[node] = p0 + hist[tid];
    }
    if (b == 0 && tid == 0) offd[N] = E;
    __syncthreads();
    if (cb <= 4096) {
        for (int i = tid; i < cb; i += 256) {
            unsigned pk = epk2[p0 + i];
            int pos = atomicAdd(&cur[(pk >> 20) & 127], 1);
            stg[pos] = pk & 0xFFFFFu;
        }
        __syncthreads();
        for (int i = tid; i < cb; i += 256) epk[p0 + i] = stg[i];
    } else {   // statistically never; correctness fallback
        for (int i = tid; i < cb; i += 256) {
            unsigned pk = epk2[p0 + i];
            int pos = atomicAdd(&cur[(pk >> 20) & 127], 1);
            epk[p0 + pos] = pk & 0xFFFFFu;
        }
    }
}

// -------- weight prep: blocks 0..25 = B fragments (fp16 hi/lo planes);
//          blocks 26..28 = q/g projection vectors --------
__global__ void k_wprep(const float* __restrict__ Wrel, const float* __restrict__ Wself,
                        const float* __restrict__ Wskip, const float* __restrict__ av,
                        const float* __restrict__ gw,
                        _Float16* __restrict__ Bh, _Float16* __restrict__ Bl,
                        float* __restrict__ q, float* __restrict__ g) {
    int bx = blockIdx.x;
    if (bx < NKS) {
        int t = bx * 256 + threadIdx.x;
        int ks = t >> 8, ct = (t >> 6) & 3, lane = t & 63;
        int col = ct * 16 + (lane & 15);
        int kb = ks * 32 + ((lane >> 4) << 3);
        _Float16* ph = Bh + (size_t)t * 8;
        _Float16* pl = Bl + (size_t)t * 8;
#pragma unroll
        for (int i = 0; i < 8; i++) {
            int k = kb + i;
            float v;
            if (k < 768) v = Wrel[(size_t)k * DD + col];
            else {
                v = Wself[(size_t)(k - 768) * DD + col];
                if (Wskip) v += Wskip[(size_t)(k - 768) * DD + col];
            }
            _Float16 h = (_Float16)v;
            ph[i] = h;
            pl[i] = (_Float16)(v - (float)h);
        }
    } else {
        int t = (bx - NKS) * 256 + threadIdx.x;
        if (t >= RR * DD) return;
        const float* wp = Wrel + (size_t)t * DD;
        float aq = 0.f, ag = 0.f;
#pragma unroll
        for (int e = 0; e < DD; e++) { float w = wp[e]; aq += w * av[e]; ag += w * gw[e]; }
        q[t] = aq; g[t] = ag;
    }
}

// ---------------- fused layer kernel: aggregate -> LDS A-tile -> MFMA ------
// Phase 1: 16-edge unrolled batches. All 16 pk + 16 wE + 16 h-row gathers are
// issued BEFORE the first scalar-branch switch block, so the in-flight load
// window is 16 deep (the branches in the AGG switches otherwise fence load
// reordering at batch boundaries).
#define AGG_EDGE(ee, wy, hh)                                       \
    switch (ee) {                                                  \
        case 0:  acc[0]  = fmaf(wy, hh, acc[0]);  break;           \
        case 1:  acc[1]  = fmaf(wy, hh, acc[1]);  break;           \
        case 2:  acc[2]  = fmaf(wy, hh, acc[2]);  break;           \
        case 3:  acc[3]  = fmaf(wy, hh, acc[3]);  break;           \
        case 4:  acc[4]  = fmaf(wy, hh, acc[4]);  break;           \
        case 5:  acc[5]  = fmaf(wy, hh, acc[5]);  break;           \
        case 6:  acc[6]  = fmaf(wy, hh, acc[6]);  break;           \
        case 7:  acc[7]  = fmaf(wy, hh, acc[7]);  break;           \
        case 8:  acc[8]  = fmaf(wy, hh, acc[8]);  break;           \
        case 9:  acc[9]  = fmaf(wy, hh, acc[9]);  break;           \
        case 10: acc[10] = fmaf(wy, hh, acc[10]); break;           \
        default: acc[11] = fmaf(wy, hh, acc[11]); break;           \
    }

__global__ void __launch_bounds__(512, 8)
k_fused(const unsigned* __restrict__ epk, const int* __restrict__ offd,
        const _Float16* __restrict__ hin16, const float* __restrict__ wE,
        const float* __restrict__ Z,
        const _Float16* __restrict__ Bh, const _Float16* __restrict__ Bl,
        const float* __restrict__ bias, float* __restrict__ out,
        _Float16* __restrict__ hout16, int N, int act) {
    __shared__ __align__(16) _Float16 At[16 * ASTR];
    __shared__ int claim;
    int tid = threadIdx.x, lane = tid & 63, w = tid >> 6;
    int nb0 = blockIdx.x * 16;
    if (tid == 0) claim = 0;
    __syncthreads();

    // ---- phase 1: waves claim nodes until the tile is done ----
    for (;;) {
        int t0 = 0;
        if (lane == 0) t0 = atomicAdd(&claim, 1);
        int nl = __builtin_amdgcn_readfirstlane(t0);
        if (nl >= 16) break;
        int node = nb0 + nl;
        _Float16* Ar = At + nl * ASTR;
        if (node >= N) {
            for (int k = lane; k < KTOT; k += 64) Ar[k] = (_Float16)0.f;
            continue;
        }
        int p0 = __builtin_amdgcn_readfirstlane(offd[node]);
        int p1 = __builtin_amdgcn_readfirstlane(offd[node + 1]);
        float acc[RR];
#pragma unroll
        for (int r = 0; r < RR; r++) acc[r] = 0.f;
        int p = p0;
        for (; p + 16 <= p1; p += 16) {
            unsigned pk[16];
            float wv[16];
            float hv[16];
#pragma unroll
            for (int i = 0; i < 16; i++) pk[i] = epk[p + i];
#pragma unroll
            for (int i = 0; i < 16; i++) wv[i] = wE[p + i];
#pragma unroll
            for (int i = 0; i < 16; i++)
                hv[i] = (float)hin16[(size_t)(pk[i] & 0xFFFFu) * DD + lane];
#pragma unroll
            for (int i = 0; i < 16; i++) {
                int e = __builtin_amdgcn_readfirstlane((int)((pk[i] >> 16) & 15u));
                AGG_EDGE(e, wv[i], hv[i]);
            }
        }
        for (; p + 4 <= p1; p += 4) {
            unsigned pk[4];
            float wv[4];
            float hv[4];
#pragma unroll
            for (int i = 0; i < 4; i++) pk[i] = epk[p + i];
#pragma unroll
            for (int i = 0; i < 4; i++) wv[i] = wE[p + i];
#pragma unroll
            for (int i = 0; i < 4; i++)
                hv[i] = (float)hin16[(size_t)(pk[i] & 0xFFFFu) * DD + lane];
#pragma unroll
            for (int i = 0; i < 4; i++) {
                int e = __builtin_amdgcn_readfirstlane((int)((pk[i] >> 16) & 15u));
                AGG_EDGE(e, wv[i], hv[i]);
            }
        }
        for (; p < p1; ++p) {
            unsigned pk = epk[p];
            float wy = wE[p];
            float hv = (float)hin16[(size_t)(pk & 0xFFFFu) * DD + lane];
            int e = __builtin_amdgcn_readfirstlane((int)((pk >> 16) & 15u));
            AGG_EDGE(e, wy, hv);
        }
        float inv = 1.f / (Z[node] + 1e-16f);
#pragma unroll
        for (int r = 0; r < RR; r++) Ar[r * DD + lane] = (_Float16)(acc[r] * inv);
        Ar[768 + lane] = hin16[(size_t)node * DD + lane];   // self/skip cols
    }
    __syncthreads();

    // ---- phase 2: waves 0-3 compute col-tiles (16 cols each) ----
    if (w < 4) {
        const half8v* Bh8 = (const half8v*)Bh;
        const half8v* Bl8 = (const half8v*)Bl;
        const _Float16* abase = At + (lane & 15) * ASTR + ((lane >> 4) << 3);
        f32x4 acc0 = {0.f, 0.f, 0.f, 0.f};
#pragma unroll 4
        for (int ks = 0; ks < NKS; ++ks) {
            half8v ah = *(const half8v*)(abase + ks * 32);
            size_t bb = (size_t)(ks * 4 + w) * 64 + lane;
            half8v bh = Bh8[bb];
            half8v bl = Bl8[bb];
            acc0 = __builtin_amdgcn_mfma_f32_16x16x32_f16(ah, bh, acc0, 0, 0, 0);
            acc0 = __builtin_amdgcn_mfma_f32_16x16x32_f16(ah, bl, acc0, 0, 0, 0);
        }

        // epilogue: D layout col=lane&15, row=(lane>>4)*4+j
        int colb = lane & 15, kg = lane >> 4;
        int c = w * 16 + colb;
        float bv = bias[c];
#pragma unroll
        for (int j = 0; j < 4; j++) {
            int row = nb0 + kg * 4 + j;
            if (row < N) {
                float v = acc0[j] + bv;
                if (act) v = v > 0.f ? v : 0.f;
                out[(size_t)row * DD + c] = v;
                if (hout16) hout16[(size_t)row * DD + c] = (_Float16)v;
            }
        }
    }
}

extern "C" void kernel_launch(void* const* d_in, const int* in_sizes, int n_in,
                              void* d_out, int out_size, void* d_ws, size_t ws_size,
                              hipStream_t stream) {
    const float* x    = (const float*)d_in[0];
    const int*   src  = (const int*)d_in[1];
    const int*   dst  = (const int*)d_in[2];
    const int*   etyp = (const int*)d_in[3];
    const float* Wemb = (const float*)d_in[4];
    const float* bemb = (const float*)d_in[5];
    const int N = in_sizes[0];
    const int E = in_sizes[1];
    const int nbuck = (N + 127) >> 7;
    const int nblk2 = (E + EPB2 - 1) / EPB2;

    const float* Wrel[3];  const float* Wself[3]; const float* bb[3];
    const float* gwv[3];   const float* gbv[3];   const float* av[3];
    for (int l = 0; l < 3; l++) {
        int o = 6 + 6 * l;
        Wrel[l]  = (const float*)d_in[o + 0];
        Wself[l] = (const float*)d_in[o + 1];
        bb[l]    = (const float*)d_in[o + 2];
        gwv[l]   = (const float*)d_in[o + 3];
        gbv[l]   = (const float*)d_in[o + 4];
        av[l]    = (const float*)d_in[o + 5];
    }
    const float* Wskip2 = (const float*)d_in[24];
    const float* Wskip3 = (const float*)d_in[25];

    // ---- workspace ----
    float* p = (float*)d_ws;
    float* h0 = p; p += (size_t)N * DD;
    float* h1 = p; p += (size_t)N * DD;
    float* h2 = p; p += (size_t)N * DD;
    _Float16* h16A = (_Float16*)p; p += (size_t)N * DD / 2;   // fp16 copy (ping)
    _Float16* h16B = (_Float16*)p; p += (size_t)N * DD / 2;   // fp16 copy (pong)
    float2* EW = (float2*)p; p += (size_t)N * RR * 2;
    float* q  = p; p += RR * DD;
    float* g  = p; p += RR * DD;
    _Float16* Bh = (_Float16*)p; p += NKS * 4 * 64 * 8 / 2;
    _Float16* Bl = (_Float16*)p; p += NKS * 4 * 64 * 8 / 2;
    unsigned* epk2 = (unsigned*)p; p += E;
    unsigned* epk  = (unsigned*)p; p += E;
    float* wEv = p; p += E;
    float* evv = p; p += E;
    float* Z   = p; p += N;
    int* bcnt  = (int*)p; p += 512;
    int* bbase = (int*)p; p += 516;
    int* bcur  = (int*)p; p += 512;
    int* offd  = (int*)p; p += N + 4;

    const int B = 256;
    k_h0<<<(N * DD + B - 1) / B, B, 0, stream>>>(x, Wemb, bemb, h0, h16A, N);

    // coalesced two-level dst-sort (once; reused by all layers)
    hipMemsetAsync(bcnt, 0, 512 * 4, stream);
    k_bh<<<nblk2, 512, 0, stream>>>(dst, bcnt, E, nbuck);
    k_bscan<<<1, 512, 0, stream>>>(bcnt, bbase, bcur, nbuck, E);
    k_bscat<<<nblk2, 512, 0, stream>>>(src, dst, etyp, bcur, epk2, E, nbuck);
    k_b2<<<nbuck, 256, 0, stream>>>(epk2, bbase, epk, offd, N, E);

    const int fblocks = (N + 15) / 16;
    // hin (f32) for scores; hin16 for gather; hout16 written for next layer
    auto layer = [&](const float* hin, const _Float16* hin16, float* hout,
                     _Float16* hout16, int l, const float* Wskip, int act) {
        k_wprep<<<NKS + 3, B, 0, stream>>>(Wrel[l], Wself[l], Wskip, av[l], gwv[l],
                                           Bh, Bl, q, g);
        k_sgw<<<(N * RR + B - 1) / B, B, 0, stream>>>(hin, q, g, gbv[l], EW, N);
        k_ew<<<(E + B - 1) / B, B, 0, stream>>>(epk, EW, wEv, evv, E);
        k_zn<<<(N + B - 1) / B, B, 0, stream>>>(evv, offd, Z, N);
        k_fused<<<fblocks, 512, 0, stream>>>(epk, offd, hin16, wEv, Z, Bh, Bl,
                                             bb[l], hout, hout16, N, act);
    };

    layer(h0, h16A, h1, h16B, 0, nullptr, 1);
    layer(h1, h16B, h2, h16A, 1, Wskip2, 1);
    layer(h2, h16A, (float*)d_out, nullptr, 2, Wskip3, 0);
}